// Round 2
// baseline (301.576 us; speedup 1.0000x reference)
//
#include <hip/hip_runtime.h>
#include <math.h>

#define DD 128
#define NSRC 8
#define LOG_2PI 1.83787706640934548356f
#define EPSF 1e-6f

// ---------------------------------------------------------------------------
// K0: detect miss_mask memory layout. Scans first N*DD/4 words (safe for all
// candidate layouts). int32 0/1 -> all words in {0,1} (flag=0). float32 ->
// words 0x3F800000 (flag bit1). packed bytes 0/1 -> words >1 but never
// 0x3F800000 (flag bit0 only).
// ---------------------------------------------------------------------------
__global__ __launch_bounds__(256) void k_detect_layout(
    const unsigned int* __restrict__ w, int n_words, int* __restrict__ flag)
{
    int i = blockIdx.x * 256 + threadIdx.x;
    if (i >= n_words) return;
    unsigned int v = w[i];
    int f = 0;
    if (v > 1u) f |= 1;
    if (v == 0x3F800000u) f |= 2;
    if (f) atomicOr(flag, f);
}

// ---------------------------------------------------------------------------
// K1: Q_s = (I-W) diag(1/sigma2_s) (I-W)^T   -> ws
// ---------------------------------------------------------------------------
__global__ __launch_bounds__(128) void k_precompute_Q(
    const float* __restrict__ W, const float* __restrict__ ls2,
    float* __restrict__ Q)
{
    __shared__ float Bs[DD][DD + 1];
    __shared__ float r[4][DD + 1];
    __shared__ float sinv[DD];
    const int tid = threadIdx.x;
    const int s   = blockIdx.x >> 5;
    const int i0  = (blockIdx.x & 31) * 4;

    for (int idx = tid; idx < DD * DD; idx += 128) {
        int row = idx >> 7, col = idx & 127;
        Bs[row][col] = (row == col ? 1.f : 0.f) - W[idx];
    }
    sinv[tid] = 1.f / fmaxf(expf(ls2[s * DD + tid]), EPSF);
    __syncthreads();
    for (int a = 0; a < 4; ++a)
        r[a][tid] = Bs[i0 + a][tid] * sinv[tid];
    __syncthreads();

    const int j = tid;
    float acc0 = 0.f, acc1 = 0.f, acc2 = 0.f, acc3 = 0.f;
    #pragma unroll 4
    for (int d = 0; d < DD; ++d) {
        float bj = Bs[j][d];
        acc0 += r[0][d] * bj;
        acc1 += r[1][d] * bj;
        acc2 += r[2][d] * bj;
        acc3 += r[3][d] * bj;
    }
    size_t base = ((size_t)s * DD + i0) * DD + j;
    Q[base         ] = acc0;
    Q[base +     DD] = acc1;
    Q[base + 2 * DD] = acc2;
    Q[base + 3 * DD] = acc3;
}

// ---------------------------------------------------------------------------
// K1b: ldS[s] = sum_d log(max(exp(ls2[s,d]), eps))   (= logdet Sigma_s)
// ---------------------------------------------------------------------------
__global__ __launch_bounds__(128) void k_logdetS(
    const float* __restrict__ ls2, float* __restrict__ ldS)
{
    __shared__ float part[2];
    const int s = blockIdx.x, tid = threadIdx.x;
    float v = logf(fmaxf(expf(ls2[s * DD + tid]), EPSF));
    for (int o = 32; o; o >>= 1) v += __shfl_down(v, o, 64);
    if ((tid & 63) == 0) part[tid >> 6] = v;
    __syncthreads();
    if (tid == 0) ldS[s] = part[0] + part[1];
}

// ---------------------------------------------------------------------------
// K2: per-sample log-likelihood via Schur complement on missing block.
// One block (128 thr) per sample. Bordered Cholesky of Q_mm (size m) with
// u = (Qx)_m appended as row m: final diag(m,m) = -u^T Q_mm^{-1} u.
// ---------------------------------------------------------------------------
__global__ __launch_bounds__(128) void k_loglik(
    const float* __restrict__ data, const float* __restrict__ mu,
    const float* __restrict__ wgt, const int* __restrict__ src,
    const void* __restrict__ miss, const int* __restrict__ layoutFlag,
    const float* __restrict__ Q, const float* __restrict__ ldS,
    float* __restrict__ out)
{
    __shared__ __align__(16) float xsh[DD];
    __shared__ float ysh[DD];
    __shared__ int   midx[DD];
    __shared__ float csc[DD + 1];
    __shared__ float tri[(DD + 1) * (DD + 2) / 2];
    __shared__ float bc[2];   // bc[0]=1/sqrt(d_k), bc[1]=d_k
    __shared__ float red[2];
    __shared__ int   sh_m;

    const int i = blockIdx.x, tid = threadIdx.x;
    if (tid == 0) sh_m = 0;
    __syncthreads();

    const int s = src[i];
    const float* Qs = Q + (size_t)s * DD * DD;

    // mask decode per detected layout (uniform branch)
    const int f = *layoutFlag;
    const size_t midx_g = (size_t)i * DD + tid;
    bool mm;
    if (f & 2)      mm = ((const float*)miss)[midx_g] != 0.f;
    else if (f & 1) mm = ((const unsigned char*)miss)[midx_g] != 0;
    else            mm = ((const int*)miss)[midx_g] != 0;

    float xv = mm ? 0.f : (data[midx_g] - mu[tid]);
    xsh[tid] = xv;
    if (mm) { int pos = atomicAdd(&sh_m, 1); midx[pos] = tid; }
    __syncthreads();
    const int m    = sh_m;
    const int dobs = DD - m;

    // y = Q_s x  (thread t -> row t), quad1 = x . y
    const float4* qrow = (const float4*)(Qs + (size_t)tid * DD);
    const float4* x4   = (const float4*)xsh;
    float acc = 0.f;
    #pragma unroll 8
    for (int d = 0; d < DD / 4; ++d) {
        float4 q = qrow[d], xx = x4[d];
        acc += q.x * xx.x + q.y * xx.y + q.z * xx.z + q.w * xx.w;
    }
    ysh[tid] = acc;
    float p = xv * acc;
    for (int o = 32; o; o >>= 1) p += __shfl_down(p, o, 64);
    if ((tid & 63) == 0) red[tid >> 6] = p;
    __syncthreads();

    // bordered triangle: rows 0..m-1 = Q_mm (gather), row m = u, diag(m,m)=0
    const int cntA = (m * (m + 1)) >> 1;
    for (int e = tid; e < cntA; e += 128) {
        int a = (int)((sqrtf(8.f * (float)e + 1.f) - 1.f) * 0.5f);
        while ((a + 1) * (a + 2) / 2 <= e) ++a;
        while (a * (a + 1) / 2 > e) --a;
        int b = e - ((a * (a + 1)) >> 1);
        tri[e] = Qs[(size_t)midx[a] * DD + midx[b]];
    }
    for (int b = tid; b < m; b += 128) tri[cntA + b] = ysh[midx[b]];
    if (tid == 0) tri[cntA + m] = 0.f;
    __syncthreads();

    float logacc = 0.f;   // (thread 0) sum_k log d_k = logdet Q_mm
    if (m > 0) {
        if (tid == 0) {
            float d0 = tri[0];
            bc[1] = d0;
            float sq = sqrtf(d0);
            bc[0] = 1.f / sq;
            tri[0] = sq;
        }
        __syncthreads();
        for (int k = 0; k < m; ++k) {
            float inv = bc[0];
            if (tid == 0) logacc += logf(bc[1]);
            for (int ii = k + 1 + tid; ii <= m; ii += 128) {
                int off = (ii * (ii + 1)) >> 1;
                float v = tri[off + k] * inv;
                tri[off + k] = v;
                csc[ii] = v;
            }
            __syncthreads();
            int qn  = m - k;
            int cnt = (qn * (qn + 1)) >> 1;
            for (int e = tid; e < cnt; e += 128) {
                int ri = (int)((sqrtf(8.f * (float)e + 1.f) - 1.f) * 0.5f);
                while ((ri + 1) * (ri + 2) / 2 <= e) ++ri;
                while (ri * (ri + 1) / 2 > e) --ri;
                int rj = e - ((ri * (ri + 1)) >> 1);
                int ii = k + 1 + ri, jj = k + 1 + rj;
                int off = (ii * (ii + 1)) >> 1;
                float v = tri[off + jj] - csc[ii] * csc[jj];
                if (ii == jj && jj == k + 1 && k + 1 < m) {
                    bc[1] = v;
                    float sq = sqrtf(v);
                    bc[0] = 1.f / sq;
                    tri[off + jj] = sq;
                } else {
                    tri[off + jj] = v;
                }
            }
            __syncthreads();
        }
    }

    if (tid == 0) {
        float quad2 = (m > 0) ? -tri[((m * (m + 1)) >> 1) + m] : 0.f;
        float quad1 = red[0] + red[1];
        float ll = -0.5f * ((quad1 - quad2) + logacc + ldS[s]
                            + (float)dobs * LOG_2PI);
        atomicAdd(out, ll * wgt[i]);
    }
}

// ---------------------------------------------------------------------------
extern "C" void kernel_launch(void* const* d_in, const int* in_sizes, int n_in,
                              void* d_out, int out_size, void* d_ws, size_t ws_size,
                              hipStream_t stream)
{
    const float* data = (const float*)d_in[0];
    const float* W    = (const float*)d_in[1];
    const float* ls2  = (const float*)d_in[2];
    const float* mu   = (const float*)d_in[3];
    const float* wgt  = (const float*)d_in[4];
    const int*   src  = (const int*)d_in[5];
    const void*  miss = (const void*)d_in[6];
    float* out = (float*)d_out;

    float* Q    = (float*)d_ws;                  // NSRC*DD*DD floats = 512 KB
    float* ldS  = Q + (size_t)NSRC * DD * DD;    // NSRC floats
    int*   flag = (int*)(ldS + NSRC);

    const int n       = in_sizes[0] / DD;        // 4096 samples
    const int n_words = (n * DD) / 4;            // safe lower bound for all layouts

    hipMemsetAsync(out, 0, sizeof(float), stream);
    hipMemsetAsync(flag, 0, sizeof(int), stream);
    hipLaunchKernelGGL(k_detect_layout, dim3((n_words + 255) / 256), dim3(256), 0, stream,
                       (const unsigned int*)miss, n_words, flag);
    hipLaunchKernelGGL(k_precompute_Q, dim3(NSRC * 32), dim3(128), 0, stream, W, ls2, Q);
    hipLaunchKernelGGL(k_logdetS, dim3(NSRC), dim3(128), 0, stream, ls2, ldS);
    hipLaunchKernelGGL(k_loglik, dim3(n), dim3(128), 0, stream,
                       data, mu, wgt, src, miss, flag, Q, ldS, out);
}

// Round 3
// 259.360 us; speedup vs baseline: 1.1628x; 1.1628x over previous
//
#include <hip/hip_runtime.h>
#include <math.h>

#define DD 128
#define NSRC 8
#define MSMALL 64
#define LOG_2PI 1.83787706640934548356f
#define EPSF 1e-6f

// e -> row index within a packed lower triangle (row r has r+1 elements).
__device__ inline int tri_row_of(int e) {
    float f = sqrtf(8.f * (float)e + 1.f);
    int r = (int)((f - 1.f) * 0.5f);
    if ((r + 1) * (r + 2) / 2 <= e) ++r;
    else if (r * (r + 1) / 2 > e) --r;
    return r;
}

// ---------------------------------------------------------------------------
// K1: fused  (a) miss_mask layout detect  (b) Q_s = (I-W) D^-1 (I-W)^T
//            (c) ldS[s] = logdet Sigma_s
// grid: NSRC*32 blocks x 128 threads. Each block also scans 512 mask words.
// ---------------------------------------------------------------------------
__global__ __launch_bounds__(128) void k_precompute(
    const float* __restrict__ W, const float* __restrict__ ls2,
    const unsigned int* __restrict__ mw, int n_words,
    float* __restrict__ Q, float* __restrict__ ldS, int* __restrict__ flag)
{
    __shared__ float Bs[DD][DD + 1];
    __shared__ float r[4][DD + 1];
    __shared__ float sinv[DD];
    __shared__ float part2[2];
    const int tid = threadIdx.x;
    const int s   = blockIdx.x >> 5;
    const int i0  = (blockIdx.x & 31) * 4;

    // --- layout detect (4 words per thread) ---
    int gid = (blockIdx.x * 128 + tid) * 4;
    int f = 0;
    #pragma unroll
    for (int t = 0; t < 4; ++t) {
        int idx = gid + t;
        if (idx < n_words) {
            unsigned int v = mw[idx];
            if (v > 1u) f |= 1;
            if (v == 0x3F800000u) f |= 2;
        }
    }
    unsigned long long bA = __ballot(f & 1);
    unsigned long long bB = __ballot(f & 2);
    if ((tid & 63) == 0) {
        int fw = (bA ? 1 : 0) | (bB ? 2 : 0);
        if (fw) atomicOr(flag, fw);
    }

    // --- Q precompute ---
    for (int idx = tid; idx < DD * DD; idx += 128) {
        int row = idx >> 7, col = idx & 127;
        Bs[row][col] = (row == col ? 1.f : 0.f) - W[idx];
    }
    sinv[tid] = 1.f / fmaxf(expf(ls2[s * DD + tid]), EPSF);
    __syncthreads();
    for (int a = 0; a < 4; ++a)
        r[a][tid] = Bs[i0 + a][tid] * sinv[tid];
    __syncthreads();

    const int j = tid;
    float acc0 = 0.f, acc1 = 0.f, acc2 = 0.f, acc3 = 0.f;
    #pragma unroll 4
    for (int d = 0; d < DD; ++d) {
        float bj = Bs[j][d];
        acc0 += r[0][d] * bj;
        acc1 += r[1][d] * bj;
        acc2 += r[2][d] * bj;
        acc3 += r[3][d] * bj;
    }
    size_t base = ((size_t)s * DD + i0) * DD + j;
    Q[base         ] = acc0;
    Q[base +     DD] = acc1;
    Q[base + 2 * DD] = acc2;
    Q[base + 3 * DD] = acc3;

    // --- ldS (one block per source) ---
    if (i0 == 0) {
        float v = logf(fmaxf(expf(ls2[s * DD + tid]), EPSF));
        for (int o = 32; o; o >>= 1) v += __shfl_down(v, o, 64);
        if ((tid & 63) == 0) part2[tid >> 6] = v;
        __syncthreads();
        if (tid == 0) ldS[s] = part2[0] + part2[1];
    }
}

// ---------------------------------------------------------------------------
// K2 fast: ONE WAVE (64 thr) per sample, wave-synchronous Cholesky, m<=64.
// Overflow samples appended to ovf_list for the fallback kernel.
// ---------------------------------------------------------------------------
__global__ __launch_bounds__(64) void k_fast(
    const float* __restrict__ data, const float* __restrict__ mu,
    const float* __restrict__ wgt, const int* __restrict__ src,
    const void* __restrict__ miss, const int* __restrict__ layoutFlag,
    const float* __restrict__ Q, const float* __restrict__ ldS,
    float* __restrict__ partial, int* __restrict__ ovf_count,
    int* __restrict__ ovf_list)
{
    __shared__ __align__(16) float xsh[DD];
    __shared__ float ysh[DD];
    __shared__ float csc[MSMALL + 1];
    __shared__ int   midx[MSMALL];
    __shared__ float tri[(MSMALL + 1) * (MSMALL + 2) / 2];

    const int i = blockIdx.x, lane = threadIdx.x;
    const int s = src[i];
    const float* Qs = Q + (size_t)s * DD * DD;
    const size_t base = (size_t)i * DD;

    // mask decode (uniform branch on detected layout)
    const int f = *layoutFlag;
    bool mm0, mm1;
    if (f & 2) {
        mm0 = ((const float*)miss)[base + lane]      != 0.f;
        mm1 = ((const float*)miss)[base + lane + 64] != 0.f;
    } else if (f & 1) {
        mm0 = ((const unsigned char*)miss)[base + lane]      != 0;
        mm1 = ((const unsigned char*)miss)[base + lane + 64] != 0;
    } else {
        mm0 = ((const int*)miss)[base + lane]      != 0;
        mm1 = ((const int*)miss)[base + lane + 64] != 0;
    }

    unsigned long long b0 = __ballot(mm0), b1 = __ballot(mm1);
    const int m = __popcll(b0) + __popcll(b1);
    if (m > MSMALL) {
        if (lane == 0) { int pos = atomicAdd(ovf_count, 1); ovf_list[pos] = i; }
        return;
    }
    unsigned long long lt = (1ull << lane) - 1ull;
    if (mm0) midx[__popcll(b0 & lt)] = lane;
    if (mm1) midx[__popcll(b0) + __popcll(b1 & lt)] = lane + 64;

    float xv0 = mm0 ? 0.f : (data[base + lane]      - mu[lane]);
    float xv1 = mm1 ? 0.f : (data[base + lane + 64] - mu[lane + 64]);
    xsh[lane] = xv0;
    xsh[lane + 64] = xv1;
    __syncthreads();

    // y = Q_s x : lane handles rows lane and lane+64
    const float4* q0 = (const float4*)(Qs + (size_t)lane * DD);
    const float4* q1 = (const float4*)(Qs + (size_t)(lane + 64) * DD);
    const float4* x4 = (const float4*)xsh;
    float a0 = 0.f, a1 = 0.f;
    #pragma unroll 8
    for (int d = 0; d < DD / 4; ++d) {
        float4 xx = x4[d];
        float4 qa = q0[d], qb = q1[d];
        a0 += qa.x * xx.x + qa.y * xx.y + qa.z * xx.z + qa.w * xx.w;
        a1 += qb.x * xx.x + qb.y * xx.y + qb.z * xx.z + qb.w * xx.w;
    }
    ysh[lane] = a0;
    ysh[lane + 64] = a1;
    float p = xv0 * a0 + xv1 * a1;
    for (int o = 32; o; o >>= 1) p += __shfl_down(p, o, 64);   // lane0: quad1
    __syncthreads();

    // bordered triangle: rows 0..m-1 = Q_mm, row m = u, diag(m,m)=0
    const int cntA = (m * (m + 1)) >> 1;
    const int cntT = cntA + m + 1;
    for (int e = lane; e < cntT; e += 64) {
        float v;
        if (e < cntA) {
            int a = tri_row_of(e);
            int b = e - ((a * (a + 1)) >> 1);
            v = Qs[(size_t)midx[a] * DD + midx[b]];
        } else if (e < cntA + m) {
            v = ysh[midx[e - cntA]];
        } else {
            v = 0.f;
        }
        tri[e] = v;
    }
    __syncthreads();

    // wave-synchronous right-looking Cholesky with border row
    float logacc = 0.f;
    for (int k = 0; k < m; ++k) {
        float dk = tri[((k * (k + 1)) >> 1) + k];   // broadcast read
        float inv = 1.f / sqrtf(dk);                // redundant on all lanes
        logacc += logf(dk);
        for (int ii = k + 1 + lane; ii <= m; ii += 64)
            csc[ii] = tri[((ii * (ii + 1)) >> 1) + k] * inv;
        __syncthreads();
        int qn  = m - k;
        int cnt = (qn * (qn + 1)) >> 1;
        for (int e = lane; e < cnt; e += 64) {
            int ri = tri_row_of(e);
            int rj = e - ((ri * (ri + 1)) >> 1);
            int ii = k + 1 + ri, jj = k + 1 + rj;
            int off = ((ii * (ii + 1)) >> 1) + jj;
            tri[off] -= csc[ii] * csc[jj];
        }
        __syncthreads();
    }

    if (lane == 0) {
        float quad2 = -tri[cntA + m];               // u^T Qmm^-1 u
        float ll = -0.5f * ((p - quad2) + logacc + ldS[s]
                            + (float)(DD - m) * LOG_2PI);
        atomicAdd(&partial[i & 63], ll * wgt[i]);
    }
}

// ---------------------------------------------------------------------------
// K2 fallback: verified R2 body, over the overflow list only (m > 64).
// ---------------------------------------------------------------------------
__global__ __launch_bounds__(128) void k_fallback(
    const float* __restrict__ data, const float* __restrict__ mu,
    const float* __restrict__ wgt, const int* __restrict__ src,
    const void* __restrict__ miss, const int* __restrict__ layoutFlag,
    const float* __restrict__ Q, const float* __restrict__ ldS,
    float* __restrict__ partial, const int* __restrict__ ovf_count,
    const int* __restrict__ ovf_list)
{
    __shared__ __align__(16) float xsh[DD];
    __shared__ float ysh[DD];
    __shared__ int   midx[DD];
    __shared__ float csc[DD + 1];
    __shared__ float tri[(DD + 1) * (DD + 2) / 2];
    __shared__ float bc[2];
    __shared__ float red[2];
    __shared__ int   sh_m;

    const int tid = threadIdx.x;
    for (int j = blockIdx.x; j < *ovf_count; j += gridDim.x) {
        const int i = ovf_list[j];
        if (tid == 0) sh_m = 0;
        __syncthreads();

        const int s = src[i];
        const float* Qs = Q + (size_t)s * DD * DD;
        const int f = *layoutFlag;
        const size_t g = (size_t)i * DD + tid;
        bool mm;
        if (f & 2)      mm = ((const float*)miss)[g] != 0.f;
        else if (f & 1) mm = ((const unsigned char*)miss)[g] != 0;
        else            mm = ((const int*)miss)[g] != 0;

        float xv = mm ? 0.f : (data[g] - mu[tid]);
        xsh[tid] = xv;
        if (mm) { int pos = atomicAdd(&sh_m, 1); midx[pos] = tid; }
        __syncthreads();
        const int m = sh_m;

        const float4* qrow = (const float4*)(Qs + (size_t)tid * DD);
        const float4* x4   = (const float4*)xsh;
        float acc = 0.f;
        #pragma unroll 8
        for (int d = 0; d < DD / 4; ++d) {
            float4 q = qrow[d], xx = x4[d];
            acc += q.x * xx.x + q.y * xx.y + q.z * xx.z + q.w * xx.w;
        }
        ysh[tid] = acc;
        float pp = xv * acc;
        for (int o = 32; o; o >>= 1) pp += __shfl_down(pp, o, 64);
        if ((tid & 63) == 0) red[tid >> 6] = pp;
        __syncthreads();

        const int cntA = (m * (m + 1)) >> 1;
        for (int e = tid; e < cntA; e += 128) {
            int a = tri_row_of(e);
            int b = e - ((a * (a + 1)) >> 1);
            tri[e] = Qs[(size_t)midx[a] * DD + midx[b]];
        }
        for (int b = tid; b < m; b += 128) tri[cntA + b] = ysh[midx[b]];
        if (tid == 0) tri[cntA + m] = 0.f;
        __syncthreads();

        float logacc = 0.f;
        if (m > 0) {
            if (tid == 0) {
                float d0 = tri[0];
                bc[1] = d0;
                float sq = sqrtf(d0);
                bc[0] = 1.f / sq;
                tri[0] = sq;
            }
            __syncthreads();
            for (int k = 0; k < m; ++k) {
                float inv = bc[0];
                if (tid == 0) logacc += logf(bc[1]);
                for (int ii = k + 1 + tid; ii <= m; ii += 128) {
                    int off = (ii * (ii + 1)) >> 1;
                    float v = tri[off + k] * inv;
                    tri[off + k] = v;
                    csc[ii] = v;
                }
                __syncthreads();
                int qn  = m - k;
                int cnt = (qn * (qn + 1)) >> 1;
                for (int e = tid; e < cnt; e += 128) {
                    int ri = tri_row_of(e);
                    int rj = e - ((ri * (ri + 1)) >> 1);
                    int ii = k + 1 + ri, jj = k + 1 + rj;
                    int off = (ii * (ii + 1)) >> 1;
                    float v = tri[off + jj] - csc[ii] * csc[jj];
                    if (ii == jj && jj == k + 1 && k + 1 < m) {
                        bc[1] = v;
                        float sq = sqrtf(v);
                        bc[0] = 1.f / sq;
                        tri[off + jj] = sq;
                    } else {
                        tri[off + jj] = v;
                    }
                }
                __syncthreads();
            }
        }

        if (tid == 0) {
            float quad2 = (m > 0) ? -tri[cntA + m] : 0.f;
            float quad1 = red[0] + red[1];
            float ll = -0.5f * ((quad1 - quad2) + logacc + ldS[s]
                                + (float)(DD - m) * LOG_2PI);
            atomicAdd(&partial[i & 63], ll * wgt[i]);
        }
        __syncthreads();
    }
}

// ---------------------------------------------------------------------------
__global__ __launch_bounds__(64) void k_reduce(
    const float* __restrict__ partial, float* __restrict__ out)
{
    int l = threadIdx.x;
    float v = partial[l];
    for (int o = 32; o; o >>= 1) v += __shfl_down(v, o, 64);
    if (l == 0) out[0] = v;
}

// ---------------------------------------------------------------------------
extern "C" void kernel_launch(void* const* d_in, const int* in_sizes, int n_in,
                              void* d_out, int out_size, void* d_ws, size_t ws_size,
                              hipStream_t stream)
{
    const float* data = (const float*)d_in[0];
    const float* W    = (const float*)d_in[1];
    const float* ls2  = (const float*)d_in[2];
    const float* mu   = (const float*)d_in[3];
    const float* wgt  = (const float*)d_in[4];
    const int*   src  = (const int*)d_in[5];
    const void*  miss = (const void*)d_in[6];
    float* out = (float*)d_out;

    float* Q        = (float*)d_ws;                    // 512 KB
    float* ldS      = Q + (size_t)NSRC * DD * DD;      // 8 floats
    float* partial  = ldS + NSRC;                      // 64 floats
    int*   flag     = (int*)(partial + 64);            // 1 int
    int*   ovf_cnt  = flag + 1;                        // 1 int
    int*   ovf_list = flag + 2;                        // 4096 ints

    const int n       = in_sizes[0] / DD;              // 4096 samples
    const int n_words = (n * DD) / 4;                  // 131072

    // zero partial + flag + ovf_cnt in one shot (contiguous 66 words)
    hipMemsetAsync(partial, 0, 66 * sizeof(float), stream);
    hipLaunchKernelGGL(k_precompute, dim3(NSRC * 32), dim3(128), 0, stream,
                       W, ls2, (const unsigned int*)miss, n_words, Q, ldS, flag);
    hipLaunchKernelGGL(k_fast, dim3(n), dim3(64), 0, stream,
                       data, mu, wgt, src, miss, flag, Q, ldS,
                       partial, ovf_cnt, ovf_list);
    hipLaunchKernelGGL(k_fallback, dim3(64), dim3(128), 0, stream,
                       data, mu, wgt, src, miss, flag, Q, ldS,
                       partial, ovf_cnt, ovf_list);
    hipLaunchKernelGGL(k_reduce, dim3(1), dim3(64), 0, stream, partial, out);
}

// Round 4
// 180.076 us; speedup vs baseline: 1.6747x; 1.4403x over previous
//
#include <hip/hip_runtime.h>
#include <math.h>

#define DD 128
#define NSRC 8
#define EMAX 32          // 32*64 = 2048 >= (m+1)(m+2)/2  ->  m <= 62 fast path
#define MFAST 62
#define LOG_2PI 1.83787706640934548356f
#define LN2F 0.69314718055994531f
#define EPSF 1e-6f

// e -> row index within a packed lower triangle (row r has r+1 elements).
__device__ inline int tri_row_of(int e) {
    float f = sqrtf(8.f * (float)e + 1.f);
    int r = (int)((f - 1.f) * 0.5f);
    if ((r + 1) * (r + 2) / 2 <= e) ++r;
    else if (r * (r + 1) / 2 > e) --r;
    return r;
}

// ---------------------------------------------------------------------------
// K1: fused  (a) miss_mask layout detect  (b) Q_s = (I-W) D^-1 (I-W)^T
//            (c) ldS[s] = logdet Sigma_s
// ---------------------------------------------------------------------------
__global__ __launch_bounds__(128) void k_precompute(
    const float* __restrict__ W, const float* __restrict__ ls2,
    const unsigned int* __restrict__ mw, int n_words,
    float* __restrict__ Q, float* __restrict__ ldS, int* __restrict__ flag)
{
    __shared__ float Bs[DD][DD + 1];
    __shared__ float r[4][DD + 1];
    __shared__ float sinv[DD];
    __shared__ float part2[2];
    const int tid = threadIdx.x;
    const int s   = blockIdx.x >> 5;
    const int i0  = (blockIdx.x & 31) * 4;

    int gid = (blockIdx.x * 128 + tid) * 4;
    int f = 0;
    #pragma unroll
    for (int t = 0; t < 4; ++t) {
        int idx = gid + t;
        if (idx < n_words) {
            unsigned int v = mw[idx];
            if (v > 1u) f |= 1;
            if (v == 0x3F800000u) f |= 2;
        }
    }
    unsigned long long bA = __ballot(f & 1);
    unsigned long long bB = __ballot(f & 2);
    if ((tid & 63) == 0) {
        int fw = (bA ? 1 : 0) | (bB ? 2 : 0);
        if (fw) atomicOr(flag, fw);
    }

    for (int idx = tid; idx < DD * DD; idx += 128) {
        int row = idx >> 7, col = idx & 127;
        Bs[row][col] = (row == col ? 1.f : 0.f) - W[idx];
    }
    sinv[tid] = 1.f / fmaxf(expf(ls2[s * DD + tid]), EPSF);
    __syncthreads();
    for (int a = 0; a < 4; ++a)
        r[a][tid] = Bs[i0 + a][tid] * sinv[tid];
    __syncthreads();

    const int j = tid;
    float acc0 = 0.f, acc1 = 0.f, acc2 = 0.f, acc3 = 0.f;
    #pragma unroll 4
    for (int d = 0; d < DD; ++d) {
        float bj = Bs[j][d];
        acc0 += r[0][d] * bj;
        acc1 += r[1][d] * bj;
        acc2 += r[2][d] * bj;
        acc3 += r[3][d] * bj;
    }
    size_t base = ((size_t)s * DD + i0) * DD + j;
    Q[base         ] = acc0;
    Q[base +     DD] = acc1;
    Q[base + 2 * DD] = acc2;
    Q[base + 3 * DD] = acc3;

    if (i0 == 0) {
        float v = logf(fmaxf(expf(ls2[s * DD + tid]), EPSF));
        for (int o = 32; o; o >>= 1) v += __shfl_down(v, o, 64);
        if ((tid & 63) == 0) part2[tid >> 6] = v;
        __syncthreads();
        if (tid == 0) ldS[s] = part2[0] + part2[1];
    }
}

// ---------------------------------------------------------------------------
// K2 fast: one wave per sample. Bordered Cholesky of Q_mm (+u border row),
// elements REGISTER-RESIDENT per lane, enumerated column-major from the
// rightmost column => per-lane slots sorted by descending column => alive
// slots form a prefix; element (m,m) is lane0 slot0. Scaled-column update
// val -= csc[row]*csc[col]*invd with double-buffered csc: ONE barrier/step.
// ---------------------------------------------------------------------------
__global__ __launch_bounds__(64) void k_fast(
    const float* __restrict__ data, const float* __restrict__ mu,
    const float* __restrict__ wgt, const int* __restrict__ src,
    const void* __restrict__ miss, const int* __restrict__ layoutFlag,
    const float* __restrict__ Q, const float* __restrict__ ldS,
    float* __restrict__ partial, int* __restrict__ ovf_count,
    int* __restrict__ ovf_list)
{
    __shared__ __align__(16) float xsh[DD];
    __shared__ float ysh[DD];
    __shared__ int   midx[DD];
    __shared__ float csc[2][64];

    const int i = blockIdx.x, lane = threadIdx.x;
    const int s = src[i];
    const float* Qs = Q + (size_t)s * DD * DD;
    const size_t base = (size_t)i * DD;

    // mask decode (uniform branch on detected layout)
    const int f = *layoutFlag;
    bool mm0, mm1;
    if (f & 2) {
        mm0 = ((const float*)miss)[base + lane]      != 0.f;
        mm1 = ((const float*)miss)[base + lane + 64] != 0.f;
    } else if (f & 1) {
        mm0 = ((const unsigned char*)miss)[base + lane]      != 0;
        mm1 = ((const unsigned char*)miss)[base + lane + 64] != 0;
    } else {
        mm0 = ((const int*)miss)[base + lane]      != 0;
        mm1 = ((const int*)miss)[base + lane + 64] != 0;
    }

    unsigned long long b0 = __ballot(mm0), b1 = __ballot(mm1);
    const int m = __popcll(b0) + __popcll(b1);
    if (m > MFAST) {
        if (lane == 0) { int pos = atomicAdd(ovf_count, 1); ovf_list[pos] = i; }
        return;
    }
    unsigned long long lt = (1ull << lane) - 1ull;
    if (mm0) midx[__popcll(b0 & lt)] = lane;
    if (mm1) midx[__popcll(b0) + __popcll(b1 & lt)] = lane + 64;

    float xv0 = mm0 ? 0.f : (data[base + lane]      - mu[lane]);
    float xv1 = mm1 ? 0.f : (data[base + lane + 64] - mu[lane + 64]);
    xsh[lane] = xv0;
    xsh[lane + 64] = xv1;
    __syncthreads();

    // y = Q_s x : lane handles rows lane and lane+64; p = x.y (lane 0)
    const float4* q0 = (const float4*)(Qs + (size_t)lane * DD);
    const float4* q1 = (const float4*)(Qs + (size_t)(lane + 64) * DD);
    const float4* x4 = (const float4*)xsh;
    float a0 = 0.f, a1 = 0.f;
    #pragma unroll 8
    for (int d = 0; d < DD / 4; ++d) {
        float4 xx = x4[d];
        float4 qa = q0[d], qb = q1[d];
        a0 += qa.x * xx.x + qa.y * xx.y + qa.z * xx.z + qa.w * xx.w;
        a1 += qb.x * xx.x + qb.y * xx.y + qb.z * xx.z + qb.w * xx.w;
    }
    ysh[lane] = a0;
    ysh[lane + 64] = a1;
    float p = xv0 * a0 + xv1 * a1;
    for (int o = 32; o; o >>= 1) p += __shfl_down(p, o, 64);
    __syncthreads();   // ysh (and midx) ready

    // decode + load slots (column-major from rightmost column of bordered tri)
    const int cntT = ((m + 1) * (m + 2)) >> 1;
    unsigned key[EMAX];
    float    val[EMAX];
    #pragma unroll
    for (int t = 0; t < EMAX; ++t) {
        key[t] = 0u; val[t] = 0.f;
        int e = lane + (t << 6);
        if (e < cntT) {
            int q  = tri_row_of(e);            // q = m - col
            int jc = m - q;                    // column
            int ir = jc + (e - ((q * (q + 1)) >> 1));   // row, jc..m
            float v;
            if (ir == m) {
                v = (jc == m) ? 0.f : ysh[midx[jc]];    // border row = u
            } else {
                v = Qs[(size_t)(midx[ir] * DD + midx[jc])];
            }
            key[t] = ((unsigned)jc << 8) | (unsigned)ir;
            val[t] = v;
            if (jc == 0) csc[0][ir] = v;       // column 0 seeds buffer A
        }
    }
    __syncthreads();

    // wave-synchronous factorization: one barrier per step
    float logacc = 0.f;
    #pragma unroll 1
    for (int k = 0; k < m; ++k) {
        const int pb = k & 1;
        float dk = csc[pb][k];
        float invd = __builtin_amdgcn_rcpf(dk);
        logacc += __log2f(dk);
        const unsigned boundA = (unsigned)(k + 1) << 8;   // alive: key >= boundA
        const unsigned boundB = (unsigned)(k + 2) << 8;   // write: key <  boundB
        #pragma unroll
        for (int t = 0; t < EMAX; ++t) {
            bool alive = (key[t] >= boundA);
            if (!__any(alive)) break;
            if (alive) {
                int ir = (int)(key[t] & 255u);
                int jc = (int)(key[t] >> 8);
                float ci = csc[pb][ir];
                float cj = csc[pb][jc];
                val[t] -= ci * cj * invd;
                if (key[t] < boundB) csc[pb ^ 1][ir] = val[t];
            }
        }
        __syncthreads();
    }

    if (lane == 0) {
        // val[0] = element (m,m) = -u^T Qmm^{-1} u ; quad = p + val[0]
        float ll = -0.5f * ((p + val[0]) + logacc * LN2F + ldS[s]
                            + (float)(DD - m) * LOG_2PI);
        atomicAdd(&partial[i & 63], ll * wgt[i]);
    }
}

// ---------------------------------------------------------------------------
// K2 fallback: verified R3 body, over the overflow list only (m > MFAST).
// ---------------------------------------------------------------------------
__global__ __launch_bounds__(128) void k_fallback(
    const float* __restrict__ data, const float* __restrict__ mu,
    const float* __restrict__ wgt, const int* __restrict__ src,
    const void* __restrict__ miss, const int* __restrict__ layoutFlag,
    const float* __restrict__ Q, const float* __restrict__ ldS,
    float* __restrict__ partial, const int* __restrict__ ovf_count,
    const int* __restrict__ ovf_list)
{
    __shared__ __align__(16) float xsh[DD];
    __shared__ float ysh[DD];
    __shared__ int   midx[DD];
    __shared__ float cscv[DD + 1];
    __shared__ float tri[(DD + 1) * (DD + 2) / 2];
    __shared__ float bc[2];
    __shared__ float red[2];
    __shared__ int   sh_m;

    const int tid = threadIdx.x;
    for (int j = blockIdx.x; j < *ovf_count; j += gridDim.x) {
        const int i = ovf_list[j];
        if (tid == 0) sh_m = 0;
        __syncthreads();

        const int s = src[i];
        const float* Qs = Q + (size_t)s * DD * DD;
        const int f = *layoutFlag;
        const size_t g = (size_t)i * DD + tid;
        bool mm;
        if (f & 2)      mm = ((const float*)miss)[g] != 0.f;
        else if (f & 1) mm = ((const unsigned char*)miss)[g] != 0;
        else            mm = ((const int*)miss)[g] != 0;

        float xv = mm ? 0.f : (data[g] - mu[tid]);
        xsh[tid] = xv;
        if (mm) { int pos = atomicAdd(&sh_m, 1); midx[pos] = tid; }
        __syncthreads();
        const int m = sh_m;

        const float4* qrow = (const float4*)(Qs + (size_t)tid * DD);
        const float4* x4   = (const float4*)xsh;
        float acc = 0.f;
        #pragma unroll 8
        for (int d = 0; d < DD / 4; ++d) {
            float4 q = qrow[d], xx = x4[d];
            acc += q.x * xx.x + q.y * xx.y + q.z * xx.z + q.w * xx.w;
        }
        ysh[tid] = acc;
        float pp = xv * acc;
        for (int o = 32; o; o >>= 1) pp += __shfl_down(pp, o, 64);
        if ((tid & 63) == 0) red[tid >> 6] = pp;
        __syncthreads();

        const int cntA = (m * (m + 1)) >> 1;
        for (int e = tid; e < cntA; e += 128) {
            int a = tri_row_of(e);
            int b = e - ((a * (a + 1)) >> 1);
            tri[e] = Qs[(size_t)midx[a] * DD + midx[b]];
        }
        for (int b = tid; b < m; b += 128) tri[cntA + b] = ysh[midx[b]];
        if (tid == 0) tri[cntA + m] = 0.f;
        __syncthreads();

        float logacc = 0.f;
        if (m > 0) {
            if (tid == 0) {
                float d0 = tri[0];
                bc[1] = d0;
                float sq = sqrtf(d0);
                bc[0] = 1.f / sq;
                tri[0] = sq;
            }
            __syncthreads();
            for (int k = 0; k < m; ++k) {
                float inv = bc[0];
                if (tid == 0) logacc += logf(bc[1]);
                for (int ii = k + 1 + tid; ii <= m; ii += 128) {
                    int off = (ii * (ii + 1)) >> 1;
                    float v = tri[off + k] * inv;
                    tri[off + k] = v;
                    cscv[ii] = v;
                }
                __syncthreads();
                int qn  = m - k;
                int cnt = (qn * (qn + 1)) >> 1;
                for (int e = tid; e < cnt; e += 128) {
                    int ri = tri_row_of(e);
                    int rj = e - ((ri * (ri + 1)) >> 1);
                    int ii = k + 1 + ri, jj = k + 1 + rj;
                    int off = (ii * (ii + 1)) >> 1;
                    float v = tri[off + jj] - cscv[ii] * cscv[jj];
                    if (ii == jj && jj == k + 1 && k + 1 < m) {
                        bc[1] = v;
                        float sq = sqrtf(v);
                        bc[0] = 1.f / sq;
                        tri[off + jj] = sq;
                    } else {
                        tri[off + jj] = v;
                    }
                }
                __syncthreads();
            }
        }

        if (tid == 0) {
            float quad2 = (m > 0) ? -tri[cntA + m] : 0.f;
            float quad1 = red[0] + red[1];
            float ll = -0.5f * ((quad1 - quad2) + logacc + ldS[s]
                                + (float)(DD - m) * LOG_2PI);
            atomicAdd(&partial[i & 63], ll * wgt[i]);
        }
        __syncthreads();
    }
}

// ---------------------------------------------------------------------------
__global__ __launch_bounds__(64) void k_reduce(
    const float* __restrict__ partial, float* __restrict__ out)
{
    int l = threadIdx.x;
    float v = partial[l];
    for (int o = 32; o; o >>= 1) v += __shfl_down(v, o, 64);
    if (l == 0) out[0] = v;
}

// ---------------------------------------------------------------------------
extern "C" void kernel_launch(void* const* d_in, const int* in_sizes, int n_in,
                              void* d_out, int out_size, void* d_ws, size_t ws_size,
                              hipStream_t stream)
{
    const float* data = (const float*)d_in[0];
    const float* W    = (const float*)d_in[1];
    const float* ls2  = (const float*)d_in[2];
    const float* mu   = (const float*)d_in[3];
    const float* wgt  = (const float*)d_in[4];
    const int*   src  = (const int*)d_in[5];
    const void*  miss = (const void*)d_in[6];
    float* out = (float*)d_out;

    float* Q        = (float*)d_ws;                    // 512 KB
    float* ldS      = Q + (size_t)NSRC * DD * DD;      // 8 floats
    float* partial  = ldS + NSRC;                      // 64 floats
    int*   flag     = (int*)(partial + 64);            // 1 int
    int*   ovf_cnt  = flag + 1;                        // 1 int
    int*   ovf_list = flag + 2;                        // 4096 ints

    const int n       = in_sizes[0] / DD;              // 4096 samples
    const int n_words = (n * DD) / 4;                  // 131072

    hipMemsetAsync(partial, 0, 66 * sizeof(float), stream);
    hipLaunchKernelGGL(k_precompute, dim3(NSRC * 32), dim3(128), 0, stream,
                       W, ls2, (const unsigned int*)miss, n_words, Q, ldS, flag);
    hipLaunchKernelGGL(k_fast, dim3(n), dim3(64), 0, stream,
                       data, mu, wgt, src, miss, flag, Q, ldS,
                       partial, ovf_cnt, ovf_list);
    hipLaunchKernelGGL(k_fallback, dim3(64), dim3(128), 0, stream,
                       data, mu, wgt, src, miss, flag, Q, ldS,
                       partial, ovf_cnt, ovf_list);
    hipLaunchKernelGGL(k_reduce, dim3(1), dim3(64), 0, stream, partial, out);
}